// Round 1
// baseline (128.632 us; speedup 1.0000x reference)
//
#include <hip/hip_runtime.h>

#define T_N       1048576
#define BLK       256
#define S_OUT     8
#define R_BLOCK   (BLK * S_OUT)      // 2048 rows per block
#define NB        (T_N / R_BLOCK)    // 512 blocks
#define NTH       (T_N / S_OUT)      // 131072 threads total
#define WARM      64                 // 0.71^64 ~ 5e-10 carry-error decay
#define HALO      (WARM + 4)         // warm-up + max shift
#define SW(u)     ((u) + ((u) >> 3)) // LDS swizzle: stride 8 -> 9, gcd(9,32)=1, conflict-free

__device__ __forceinline__ float pp_step(float c, float p, float mr, float miss,
                                         float omev, float evc) {
    float last = (c > mr) ? fmaf(c - mr, miss, mr) : c;
    return fmaf(last + p, omev, -evc);
}

__global__ __launch_bounds__(BLK) void k_main(
    const float* __restrict__ x,
    const float* __restrict__ f0p, const float* __restrict__ fcp,
    const float* __restrict__ kp,  const float* __restrict__ nnp,
    const float* __restrict__ dpp, const float* __restrict__ evp,
    const float* __restrict__ evcp,const float* __restrict__ mrp,
    const float* __restrict__ missp,
    const float* __restrict__ wr1p,const float* __restrict__ wr2p,
    const float* __restrict__ wz1p,const float* __restrict__ wz2p,
    const int*   __restrict__ epp,
    float* __restrict__ out, float* __restrict__ Bthr, float* __restrict__ Bblk)
{
    __shared__ float s_prec[SW(R_BLOCK + HALO - 1) + 1];
    __shared__ float s_cG[SW(R_BLOCK + 4 - 1) + 1];
    __shared__ float s_cA[SW(R_BLOCK + 4 - 1) + 1];
    __shared__ float s_B[BLK];

    const int b = blockIdx.x, t = threadIdx.x;
    const int row0 = b * R_BLOCK;

    const float f0 = *f0p, fc = *fcp, kk = *kp, nn = *nnp;
    const float dp = *dpp, ev = *evp, evc = *evcp, mr = *mrp, miss = *missp;
    const float wr1 = *wr1p, wr2 = *wr2p, wz1 = *wz1p, wz2 = *wz2p;
    const int ep = *epp;
    const float omev = 1.0f - ev;
    const float cimp = 1.49f / nn;
    const float f0mfc = f0 - fc;

    const float rid = rintf(x[8]);                    // jnp.round == rint (half-even)
    const int shift = (rid == 3723.0f || rid == 870.0f) ? 1 : 4;
    const float pp0 = x[7] - x[6];                    // total_prec[0] - prec[0]

    // Stage prec column (scan-1 input) with warm-up halo. Global read once, coalesced-ish.
    for (int u = t; u < R_BLOCK + HALO; u += BLK) {
        int r = row0 - HALO + u;
        s_prec[SW(u)] = (r >= 0) ? x[r * 9 + 6] : 0.0f;
    }
    // Stage per-row q coefficients for rows [row0-4, row0+R_BLOCK). Adjacent lanes read
    // adjacent 36B rows -> cache lines fetched sequentially, each exactly once.
    for (int u = t; u < R_BLOCK + 4; u += BLK) {
        int r = row0 - 4 + u;
        float cg = 0.0f, ca = 0.0f;
        if (r >= 0) {
            const float* row = x + r * 9;
            float gl = row[0], imp = row[2], ar = row[3], sl = row[4], tp = row[7];
            float ft = fmaf(f0mfc, __expf(-kk * tp), fc);
            cg = gl * ar * (1.0f - ft) * 0.001f;
            ca = sqrtf(imp * ar) * cimp * sqrtf(sl);
        }
        s_cG[SW(u)] = cg;
        s_cA[SW(u)] = ca;
    }
    __syncthreads();

    // ---- scan-1: per-thread warm-up (contractive recurrence, slope <= 1-ev = 0.71) ----
    const int i0 = row0 + t * S_OUT;       // this thread's output range [i0, i0+S)
    const int rb = i0 - shift;             // row needed for first output
    int rr = rb - WARM; if (rr < 0) rr = 0;
    float c = (rr == 0) ? pp0 : 0.0f;      // exact init at row 0, else decayed-away guess
    const int rs = (rb < 0) ? 0 : rb;
    for (; rr < rs; ++rr)
        c = pp_step(c, s_prec[SW(rr - row0 + HALO)], mr, miss, omev, evc);

    // ---- main: q + local (h_in = 0) scan-2 ----
    float h = 0.0f;
    for (int j = 0; j < S_OUT; ++j) {
        const int i = i0 + j;
        const int r = i - shift;
        float qs = 0.0f;
        if (r >= 0) {
            float pre = fmaxf(c, 0.0f);                      // relu'd prec_pre; carry stays raw
            int ci = r - row0 + 4;
            float qg = fmaxf(pre * s_cG[SW(ci)], 0.0f);
            float di = fmaxf(fmaf(pre, 0.001f, -dp), 0.0f);
            float qi = fmaxf(s_cA[SW(ci)] * __powf(di, 5.0f / 3.0f), 0.0f);
            qs = qg + qi;
            c = pp_step(c, s_prec[SW(r - row0 + HALO)], mr, miss, omev, evc);
        }
        h = fmaf(wr1, h, wr2 * qs);        // q_shift[0]=0 keeps h=0 through i=0: matches ref
        out[i] = (ep > 10) ? fmaf(wz1, h, wz2 * qs) : qs;
    }

    // thread aggregate B (A = wr1^S is uniform); force 0 when epoch<=10 so fix-up is a no-op
    float Bv = (ep > 10) ? h : 0.0f;
    s_B[t] = Bv;
    Bthr[b * BLK + t] = Bv;
    __syncthreads();
    if (t == 0) {
        const float at = powf(wr1, (float)S_OUT);
        float acc = 0.0f;
        for (int u = 0; u < BLK; ++u) acc = fmaf(at, acc, s_B[u]);
        Bblk[b] = acc;
    }
}

// Cross-block carry propagation + correction: out[i0+j] += wz1 * wr1^(j+1) * h_in
__global__ __launch_bounds__(BLK) void k_fix(
    float* __restrict__ out,
    const float* __restrict__ Bthr, const float* __restrict__ Bblk,
    const float* __restrict__ wr1p, const float* __restrict__ wz1p)
{
    __shared__ float sBb[NB];
    __shared__ float sB[BLK];
    __shared__ float carr[BLK];
    const int b = blockIdx.x, t = threadIdx.x;
    const float wr1 = *wr1p, wz1 = *wz1p;
    for (int u = t; u < NB; u += BLK) sBb[u] = Bblk[u];
    sB[t] = Bthr[b * BLK + t];
    __syncthreads();
    if (t == 0) {
        const float ab = powf(wr1, (float)R_BLOCK);
        float c0 = 0.0f;
        for (int u = 0; u < b; ++u) c0 = fmaf(ab, c0, sBb[u]);   // carry into block b
        const float at = powf(wr1, (float)S_OUT);
        float cth = c0;
        for (int u = 0; u < BLK; ++u) { carr[u] = cth; cth = fmaf(at, cth, sB[u]); }
    }
    __syncthreads();
    float hin = carr[t];
    if (hin != 0.0f) {                     // epoch<=10 or true-zero carry: correction exactly 0
        int i = b * R_BLOCK + t * S_OUT;
        float p = hin * wz1;
        for (int j = 0; j < S_OUT; ++j) {
            p *= wr1;
            out[i + j] += p;
        }
    }
}

extern "C" void kernel_launch(void* const* d_in, const int* in_sizes, int n_in,
                              void* d_out, int out_size, void* d_ws, size_t ws_size,
                              hipStream_t stream) {
    const float* x = (const float*)d_in[0];
    float* out  = (float*)d_out;
    float* Bthr = (float*)d_ws;            // NTH floats (512 KB)
    float* Bblk = Bthr + NTH;              // NB floats

    k_main<<<NB, BLK, 0, stream>>>(x,
        (const float*)d_in[1],  (const float*)d_in[2],  (const float*)d_in[3],
        (const float*)d_in[4],  (const float*)d_in[5],  (const float*)d_in[6],
        (const float*)d_in[7],  (const float*)d_in[8],  (const float*)d_in[9],
        (const float*)d_in[10], (const float*)d_in[11], (const float*)d_in[12],
        (const float*)d_in[13], (const int*)d_in[14],
        out, Bthr, Bblk);

    k_fix<<<NB, BLK, 0, stream>>>(out, Bthr, Bblk,
        (const float*)d_in[10], (const float*)d_in[12]);
}